// Round 6
// baseline (404.184 us; speedup 1.0000x reference)
//
#include <hip/hip_runtime.h>
#include <math.h>

#define SEQL 197
#define HD 768
#define NH 12
#define DHD 64
#define BATCH 64
#define OUTD 1000

typedef unsigned short ushort_t;
typedef __attribute__((ext_vector_type(8))) short bf16x8;
typedef __attribute__((ext_vector_type(4))) float f32x4;

static __device__ __forceinline__ unsigned short f2bf(float f) {
    union { float f; unsigned u; } v; v.f = f;
    unsigned r = v.u + 0x7fff + ((v.u >> 16) & 1);
    return (unsigned short)(r >> 16);
}

static __device__ __forceinline__ void gload16(const ushort_t* g, ushort_t* l) {
    __builtin_amdgcn_global_load_lds(
        (const __attribute__((address_space(1))) unsigned int*)g,
        (__attribute__((address_space(3))) unsigned int*)l, 16, 0, 0);
}

// ---------------- positional embedding table ----------------
__global__ void k_pos(float* __restrict__ pos) {
    int i = blockIdx.x * 256 + threadIdx.x;
    if (i >= SEQL * HD) return;
    int s = i / HD, d = i % HD;
    float f = (float)(d & ~1);
    float r = powf(10000.0f, -f / (float)HD);
    float a = (float)s * r;
    pos[i] = (d & 1) ? cosf(a) : sinf(a);
}

// ---------------- cls row of tokens ----------------
__global__ void k_cls(const float* __restrict__ cls_tok, const float* __restrict__ pos,
                      float* __restrict__ tok) {
    int i = blockIdx.x * 256 + threadIdx.x;
    if (i >= BATCH * HD) return;
    int b = i / HD, e = i % HD;
    tok[(b * SEQL) * HD + e] = cls_tok[e] + pos[e];
}

// ---------------- W (f32 [K][N]) -> W^T bf16 [N][K], K=N=768 ----------------
__global__ void k_cvtW(const float* __restrict__ W, ushort_t* __restrict__ WT) {
    int idx = blockIdx.x * 256 + threadIdx.x;       // 0 .. 768*192
    if (idx >= 768 * 192) return;
    int k = idx / 192, nq = idx % 192;
    float4 w = *(const float4*)&W[k * 768 + nq * 4];
    WT[(nq * 4 + 0) * 768 + k] = f2bf(w.x);
    WT[(nq * 4 + 1) * 768 + k] = f2bf(w.y);
    WT[(nq * 4 + 2) * 768 + k] = f2bf(w.z);
    WT[(nq * 4 + 3) * 768 + k] = f2bf(w.w);
}

// ---------------- Wq/Wk/Wv [12][64 d][64 e] f32 -> wt bf16 [3][12][64 e][64 d] ----
__global__ void k_cvtWqkv(const float* __restrict__ Wq, const float* __restrict__ Wk,
                          const float* __restrict__ Wv, ushort_t* __restrict__ wt) {
    int idx = blockIdx.x * 256 + threadIdx.x;       // over 3*12*64*16 = 36864
    if (idx >= 36864) return;
    int dq = idx & 15;
    int e  = (idx >> 4) & 63;
    int h  = (idx >> 10) % 12;
    int pj = idx / 12288;
    const float* W = (pj == 0) ? Wq : (pj == 1) ? Wk : Wv;
    ushort4 o;
    o.x = f2bf(W[(h * 64 + dq * 4 + 0) * 64 + e]);
    o.y = f2bf(W[(h * 64 + dq * 4 + 1) * 64 + e]);
    o.z = f2bf(W[(h * 64 + dq * 4 + 2) * 64 + e]);
    o.w = f2bf(W[(h * 64 + dq * 4 + 3) * 64 + e]);
    *(ushort4*)&wt[(size_t)((pj * 12 + h) * 64 + e) * 64 + dq * 4] = o;
}

// ---------------- gather patches -> bf16 A [12544][768] ----------------
__global__ void k_prep_patches(const float* __restrict__ img, ushort_t* __restrict__ Ae) {
    int idx = blockIdx.x * 256 + threadIdx.x;       // 0 .. 12544*192
    int m = idx / 192, kq = idx % 192;
    int k0 = kq * 4;
    int c = k0 >> 8, rem = k0 & 255, ir = rem >> 4, jc = rem & 15;
    int b = m / 196, pi = m % 196;
    int pr = pi / 14, pc = pi % 14;
    float4 v = *(const float4*)&img[((b * 3 + c) * 224 + pr * 16 + ir) * 224 + pc * 16 + jc];
    ushort4 o;
    o.x = f2bf(v.x); o.y = f2bf(v.y); o.z = f2bf(v.z); o.w = f2bf(v.w);
    *(ushort4*)&Ae[m * 768 + k0] = o;
}

// ---------------- bf16 MFMA GEMM, 128x128 tile, BK=64, 4 waves ----------------
template <int MODE>
__launch_bounds__(256)
__global__ void k_gemm_bf16(const ushort_t* __restrict__ A, const ushort_t* __restrict__ Bt,
                            const float* __restrict__ bias, const float* __restrict__ pos,
                            float* __restrict__ out, int Mtot) {
    __shared__ ushort_t As[128 * 64];
    __shared__ ushort_t Bs[128 * 64];
    const int m0 = blockIdx.x * 128;
    const int n0 = blockIdx.y * 128;
    const int tid = threadIdx.x;
    const int lane = tid & 63, wave = tid >> 6;
    const int wm = wave >> 1, wn = wave & 1;

    f32x4 acc[4][4];
#pragma unroll
    for (int i = 0; i < 4; ++i)
#pragma unroll
        for (int j = 0; j < 4; ++j)
#pragma unroll
            for (int r = 0; r < 4; ++r) acc[i][j][r] = 0.f;

    for (int kt = 0; kt < 12; ++kt) {
        const int k0 = kt * 64;
#pragma unroll
        for (int t = 0; t < 4; ++t) {
            int c = (wave << 2) | t;
            int o = c * 1024 + lane * 16;
            int row = o >> 7;
            int inner = o & 127;
            int col = (inner ^ ((row & 7) << 4)) >> 1;
            gload16(&A[(size_t)(m0 + row) * 768 + k0 + col], &As[c * 512]);
            gload16(&Bt[(size_t)(n0 + row) * 768 + k0 + col], &Bs[c * 512]);
        }
        __syncthreads();
#pragma unroll
        for (int ks = 0; ks < 2; ++ks) {
            const int cbyte = ks * 64 + (lane >> 4) * 16;
            bf16x8 af[4], bf[4];
#pragma unroll
            for (int mi = 0; mi < 4; ++mi) {
                int row = wm * 64 + mi * 16 + (lane & 15);
                af[mi] = *(const bf16x8*)((const char*)As + row * 128 + (cbyte ^ ((row & 7) << 4)));
            }
#pragma unroll
            for (int ni = 0; ni < 4; ++ni) {
                int n = wn * 64 + ni * 16 + (lane & 15);
                bf[ni] = *(const bf16x8*)((const char*)Bs + n * 128 + (cbyte ^ ((n & 7) << 4)));
            }
#pragma unroll
            for (int mi = 0; mi < 4; ++mi)
#pragma unroll
                for (int ni = 0; ni < 4; ++ni)
                    acc[mi][ni] = __builtin_amdgcn_mfma_f32_16x16x32_bf16(af[mi], bf[ni], acc[mi][ni], 0, 0, 0);
        }
        __syncthreads();
    }

    const int colb = n0 + wn * 64 + (lane & 15);
    const int rowb = m0 + wm * 64 + (lane >> 4) * 4;
#pragma unroll
    for (int ni = 0; ni < 4; ++ni) {
        const int n = colb + ni * 16;
        const float bn = bias[n];
#pragma unroll
        for (int mi = 0; mi < 4; ++mi) {
#pragma unroll
            for (int r = 0; r < 4; ++r) {
                int m = rowb + mi * 16 + r;
                if (MODE == 0) {
                    int b = m / 196, s = 1 + m % 196;
                    out[((b * SEQL) + s) * HD + n] = acc[mi][ni][r] + bn + pos[s * HD + n];
                } else {
                    if (m < Mtot) {
                        float* p = &out[(size_t)m * HD + n];
                        *p = *p + fmaxf(acc[mi][ni][r] + bn, 0.f);
                    }
                }
            }
        }
    }
}

// ---------------- 2D LayerNorm stats (mean, rsigma) per image ----------------
__global__ void k_lnstats(const float* __restrict__ buf, float* __restrict__ stats, int which) {
    int b = blockIdx.x;
    const float* p = buf + (size_t)b * SEQL * HD;
    float s = 0.f, s2 = 0.f;
    const int NV = SEQL * HD / 4;
    for (int i = threadIdx.x; i < NV; i += 256) {
        float4 v = ((const float4*)p)[i];
        s += v.x + v.y + v.z + v.w;
        s2 += v.x * v.x + v.y * v.y + v.z * v.z + v.w * v.w;
    }
    __shared__ float rs[8], rs2[8];
#pragma unroll
    for (int off = 32; off > 0; off >>= 1) {
        s += __shfl_down(s, off);
        s2 += __shfl_down(s2, off);
    }
    int lane = threadIdx.x & 63, w = threadIdx.x >> 6;
    if (lane == 0) { rs[w] = s; rs2[w] = s2; }
    __syncthreads();
    if (threadIdx.x == 0) {
        float S = 0.f, S2 = 0.f;
        for (int i = 0; i < 4; ++i) { S += rs[i]; S2 += rs2[i]; }
        const float inv_n = 1.0f / (float)(SEQL * HD);
        float mu = S * inv_n;
        float var = S2 * inv_n - mu * mu;
        stats[which * 128 + b * 2] = mu;
        stats[which * 128 + b * 2 + 1] = rsqrtf(var + 1e-5f);
    }
}

// ---------------- LN1 apply -> bf16 xb [12608][768] ----------------
__global__ void k_ln1(const float* __restrict__ tok, const float* __restrict__ stats,
                      const float* __restrict__ g1, const float* __restrict__ b1,
                      ushort_t* __restrict__ xb) {
    int i = blockIdx.x * 256 + threadIdx.x;
    if (i >= BATCH * SEQL * HD / 4) return;
    int e4 = i * 4;
    int m = e4 / HD, kk = e4 % HD;
    int b = m / SEQL, s = m % SEQL;
    float mu = stats[b * 2], rsg = stats[b * 2 + 1];
    float4 t = *(const float4*)&tok[e4];
    float4 g = *(const float4*)&g1[s * HD + kk];
    float4 bb = *(const float4*)&b1[s * HD + kk];
    ushort4 o;
    o.x = f2bf((t.x - mu) * rsg * g.x + bb.x);
    o.y = f2bf((t.y - mu) * rsg * g.y + bb.y);
    o.z = f2bf((t.z - mu) * rsg * g.z + bb.z);
    o.w = f2bf((t.w - mu) * rsg * g.w + bb.w);
    *(ushort4*)&xb[e4] = o;
}

// ---------------- MFMA QKV: per (half, h, b), 128 rows x 64 e x 3 proj ----------
// q,k out: bf16 [bh][256][64] (pad rows untouched). vt out: bf16 [bh][64][256].
__launch_bounds__(256)
__global__ void k_qkv_mfma(const ushort_t* __restrict__ xb, const ushort_t* __restrict__ wt,
                           const float* __restrict__ bq, const float* __restrict__ bk,
                           const float* __restrict__ bv,
                           ushort_t* __restrict__ q16, ushort_t* __restrict__ k16,
                           ushort_t* __restrict__ vt16) {
    const int half = blockIdx.x, h = blockIdx.y, b = blockIdx.z;
    __shared__ ushort_t Xs[128 * 64];   // swizzled X tile [128 s][64 d]
    __shared__ ushort_t Ob[128 * 72];   // bounce: Q/K [128][72]; V [64][132]
    const int tid = threadIdx.x;
    const int lane = tid & 63, wave = tid >> 6;
    const int l16 = lane & 15, l4 = lane >> 4;
    const int sbase = half * 128;

    // stage X tile (rows s_local 0..127, cols d 0..63 of head h)
    const size_t xrow0 = (size_t)b * SEQL + sbase;
#pragma unroll
    for (int t = 0; t < 4; ++t) {
        int c = (wave << 2) | t;
        int row = (c << 3) | (lane >> 3);
        int col = ((lane & 7) ^ (row & 7)) << 3;
        gload16(&xb[(xrow0 + row) * 768 + h * 64 + col], &Xs[c * 512]);
    }
    __syncthreads();

    // A fragments (live across all 3 projections)
    bf16x8 af[2][2];
#pragma unroll
    for (int mi = 0; mi < 2; ++mi)
#pragma unroll
        for (int kk = 0; kk < 2; ++kk) {
            int row = wave * 32 + mi * 16 + l16;
            af[mi][kk] = *(const bf16x8*)((const char*)Xs + row * 128 +
                                          ((kk * 64 + l4 * 16) ^ ((row & 7) << 4)));
        }

    for (int pj = 0; pj < 3; ++pj) {
        const float* bptr = (pj == 0) ? bq : (pj == 1) ? bk : bv;
        bf16x8 wf[4][2];
#pragma unroll
        for (int ni = 0; ni < 4; ++ni)
#pragma unroll
            for (int kk = 0; kk < 2; ++kk)
                wf[ni][kk] = *(const bf16x8*)&wt[(size_t)((pj * 12 + h) * 64 + ni * 16 + l16) * 64 + kk * 32 + l4 * 8];

        f32x4 acc[2][4];
#pragma unroll
        for (int mi = 0; mi < 2; ++mi)
#pragma unroll
            for (int ni = 0; ni < 4; ++ni) {
                acc[mi][ni][0] = 0.f; acc[mi][ni][1] = 0.f;
                acc[mi][ni][2] = 0.f; acc[mi][ni][3] = 0.f;
            }
#pragma unroll
        for (int mi = 0; mi < 2; ++mi)
#pragma unroll
            for (int ni = 0; ni < 4; ++ni) {
                acc[mi][ni] = __builtin_amdgcn_mfma_f32_16x16x32_bf16(af[mi][0], wf[ni][0], acc[mi][ni], 0, 0, 0);
                acc[mi][ni] = __builtin_amdgcn_mfma_f32_16x16x32_bf16(af[mi][1], wf[ni][1], acc[mi][ni], 0, 0, 0);
            }

        float bias4[4];
#pragma unroll
        for (int ni = 0; ni < 4; ++ni) bias4[ni] = bptr[h * 64 + ni * 16 + l16];

        if (pj < 2) {
            // C layout: col e = lane&15, row s_local = (lane>>4)*4 + r
#pragma unroll
            for (int mi = 0; mi < 2; ++mi)
#pragma unroll
                for (int ni = 0; ni < 4; ++ni)
#pragma unroll
                    for (int r = 0; r < 4; ++r) {
                        int sl = wave * 32 + mi * 16 + l4 * 4 + r;
                        Ob[sl * 72 + ni * 16 + l16] = f2bf(acc[mi][ni][r] + bias4[ni]);
                    }
            __syncthreads();
            ushort_t* dst = (pj == 0) ? q16 : k16;
            const size_t qkb = (size_t)(b * 12 + h) * 256 * 64;
            int row = tid >> 1, hw = tid & 1;
            int s = sbase + row;
            if (s < SEQL) {
#pragma unroll
                for (int i = 0; i < 4; ++i)
                    *(uint4*)&dst[qkb + (size_t)s * 64 + hw * 32 + i * 8] =
                        *(const uint4*)&Ob[row * 72 + hw * 32 + i * 8];
            }
            __syncthreads();
        } else {
            // V: store transposed into Ob [64 e][132 sl]
#pragma unroll
            for (int mi = 0; mi < 2; ++mi)
#pragma unroll
                for (int ni = 0; ni < 4; ++ni)
#pragma unroll
                    for (int r = 0; r < 4; ++r) {
                        int sl = wave * 32 + mi * 16 + l4 * 4 + r;
                        Ob[(ni * 16 + l16) * 132 + sl] = f2bf(acc[mi][ni][r] + bias4[ni]);
                    }
            __syncthreads();
            const size_t vbase = (size_t)(b * 12 + h) * 64 * 256;
            int e = tid >> 2, qq = tid & 3;
#pragma unroll
            for (int i = 0; i < 8; ++i) {
                int s = sbase + qq * 32 + i * 4;
                if (s < SEQL)
                    *(uint2*)&vt16[vbase + (size_t)e * 256 + s] =
                        *(const uint2*)&Ob[e * 132 + qq * 32 + i * 4];
            }
        }
    }
}

// ---------------- MFMA flash attention + residual ----------------
__launch_bounds__(512)
__global__ void k_attn_mfma(const ushort_t* __restrict__ q, const ushort_t* __restrict__ k,
                            const ushort_t* __restrict__ vt, const float* __restrict__ tok,
                            float* __restrict__ out) {
    const int h = blockIdx.x, b = blockIdx.y;
    const int tid = threadIdx.x;
    const int wave = tid >> 6, lane = tid & 63;
    const int l16 = lane & 15, l4 = lane >> 4;
    __shared__ ushort_t Ps[8][32 * 72];

    const size_t qkbase = (size_t)(b * 12 + h) * 256 * 64;
    const size_t vbase  = (size_t)(b * 12 + h) * 64 * 256;
    const int r0 = wave * 32;

    bf16x8 qa[2][2];
#pragma unroll
    for (int mi = 0; mi < 2; ++mi)
#pragma unroll
        for (int kk = 0; kk < 2; ++kk)
            qa[mi][kk] = *(const bf16x8*)&q[qkbase + (size_t)(r0 + mi * 16 + l16) * 64 + kk * 32 + l4 * 8];

    f32x4 oacc[2][4];
    float m_s[2][4], l_s[2][4];
#pragma unroll
    for (int mi = 0; mi < 2; ++mi) {
#pragma unroll
        for (int r = 0; r < 4; ++r) {
            m_s[mi][r] = -INFINITY;
            l_s[mi][r] = 0.f;
        }
#pragma unroll
        for (int ne = 0; ne < 4; ++ne)
#pragma unroll
            for (int r = 0; r < 4; ++r) oacc[mi][ne][r] = 0.f;
    }

    ushort_t* myP = &Ps[wave][0];

    for (int tt = 0; tt < 4; ++tt) {
        const int t0 = tt * 64;
        bf16x8 kf[4][2];
#pragma unroll
        for (int ni = 0; ni < 4; ++ni)
#pragma unroll
            for (int kk = 0; kk < 2; ++kk)
                kf[ni][kk] = *(const bf16x8*)&k[qkbase + (size_t)(t0 + ni * 16 + l16) * 64 + kk * 32 + l4 * 8];

        f32x4 sa[2][4];
#pragma unroll
        for (int mi = 0; mi < 2; ++mi)
#pragma unroll
            for (int ni = 0; ni < 4; ++ni) {
                f32x4 z;
                z[0] = 0.f; z[1] = 0.f; z[2] = 0.f; z[3] = 0.f;
                z = __builtin_amdgcn_mfma_f32_16x16x32_bf16(qa[mi][0], kf[ni][0], z, 0, 0, 0);
                sa[mi][ni] = __builtin_amdgcn_mfma_f32_16x16x32_bf16(qa[mi][1], kf[ni][1], z, 0, 0, 0);
            }

#pragma unroll
        for (int mi = 0; mi < 2; ++mi) {
#pragma unroll
            for (int r = 0; r < 4; ++r) {
                float sv[4];
                float mt = -INFINITY;
#pragma unroll
                for (int ni = 0; ni < 4; ++ni) {
                    float s = sa[mi][ni][r] * 0.125f;
                    if (t0 + ni * 16 + l16 >= SEQL) s = -1e30f;
                    sv[ni] = s;
                    mt = fmaxf(mt, s);
                }
                mt = fmaxf(mt, __shfl_xor(mt, 1));
                mt = fmaxf(mt, __shfl_xor(mt, 2));
                mt = fmaxf(mt, __shfl_xor(mt, 4));
                mt = fmaxf(mt, __shfl_xor(mt, 8));
                float mn = fmaxf(m_s[mi][r], mt);
                float alpha = __expf(m_s[mi][r] - mn);
                m_s[mi][r] = mn;
                float rsum = 0.f;
#pragma unroll
                for (int ni = 0; ni < 4; ++ni) {
                    float p = __expf(sv[ni] - mn);
                    rsum += p;
                    myP[(mi * 16 + l4 * 4 + r) * 72 + ni * 16 + l16] = f2bf(p);
                }
                rsum += __shfl_xor(rsum, 1);
                rsum += __shfl_xor(rsum, 2);
                rsum += __shfl_xor(rsum, 4);
                rsum += __shfl_xor(rsum, 8);
                l_s[mi][r] = l_s[mi][r] * alpha + rsum;
#pragma unroll
                for (int ne = 0; ne < 4; ++ne) oacc[mi][ne][r] *= alpha;
            }
        }

        bf16x8 vf[4][2];
#pragma unroll
        for (int ne = 0; ne < 4; ++ne)
#pragma unroll
            for (int kk = 0; kk < 2; ++kk)
                vf[ne][kk] = *(const bf16x8*)&vt[vbase + (size_t)(ne * 16 + l16) * 256 + t0 + kk * 32 + l4 * 8];
        bf16x8 pa[2][2];
#pragma unroll
        for (int mi = 0; mi < 2; ++mi)
#pragma unroll
            for (int kk = 0; kk < 2; ++kk)
                pa[mi][kk] = *(const bf16x8*)&myP[(mi * 16 + l16) * 72 + kk * 32 + l4 * 8];
#pragma unroll
        for (int mi = 0; mi < 2; ++mi)
#pragma unroll
            for (int ne = 0; ne < 4; ++ne) {
                oacc[mi][ne] = __builtin_amdgcn_mfma_f32_16x16x32_bf16(pa[mi][0], vf[ne][0], oacc[mi][ne], 0, 0, 0);
                oacc[mi][ne] = __builtin_amdgcn_mfma_f32_16x16x32_bf16(pa[mi][1], vf[ne][1], oacc[mi][ne], 0, 0, 0);
            }
    }

#pragma unroll
    for (int mi = 0; mi < 2; ++mi) {
#pragma unroll
        for (int r = 0; r < 4; ++r) {
            int row = r0 + mi * 16 + l4 * 4 + r;
            if (row < SEQL) {
                float inv = 1.0f / l_s[mi][r];
                size_t off = ((size_t)(b * SEQL + row)) * HD + h * 64;
#pragma unroll
                for (int ne = 0; ne < 4; ++ne) {
                    int e = ne * 16 + l16;
                    out[off + e] = oacc[mi][ne][r] * inv + tok[off + e];
                }
            }
        }
    }
}

// ---------------- LN2 apply -> bf16 A for encoder GEMM ----------------
__global__ void k_ln2apply(const float* __restrict__ outb, const float* __restrict__ stats,
                           const float* __restrict__ g2, const float* __restrict__ b2,
                           ushort_t* __restrict__ x) {
    int i = blockIdx.x * 256 + threadIdx.x;
    if (i >= BATCH * SEQL * HD / 4) return;
    int e4 = i * 4;
    int m = e4 / HD, kk = e4 % HD;
    int b = m / SEQL, s = m % SEQL;
    float mu = stats[128 + b * 2], rsg = stats[128 + b * 2 + 1];
    float4 t = *(const float4*)&outb[e4];
    float4 g = *(const float4*)&g2[s * HD + kk];
    float4 bb = *(const float4*)&b2[s * HD + kk];
    ushort4 o;
    o.x = f2bf((t.x - mu) * rsg * g.x + bb.x);
    o.y = f2bf((t.y - mu) * rsg * g.y + bb.y);
    o.z = f2bf((t.z - mu) * rsg * g.z + bb.z);
    o.w = f2bf((t.w - mu) * rsg * g.w + bb.w);
    *(ushort4*)&x[e4] = o;
}

// ---------------- classifier head + softmax ----------------
__launch_bounds__(256)
__global__ void k_head(const float* __restrict__ out, const float* __restrict__ Wo,
                       const float* __restrict__ bo, float* __restrict__ dout) {
    const int b = blockIdx.x, tid = threadIdx.x;
    __shared__ float cls[768];
    __shared__ float red[256];
    for (int i = tid; i < 192; i += 256)
        *(float4*)&cls[i * 4] = *(const float4*)&out[(b * SEQL) * HD + i * 4];
    __syncthreads();

    const int o0 = tid * 4;
    const bool ok = (o0 < OUTD);
    float4 acc = {0.f, 0.f, 0.f, 0.f};
    if (ok) {
        acc = *(const float4*)&bo[o0];
        for (int e = 0; e < 768; ++e) {
            float c = cls[e];
            float4 w = *(const float4*)&Wo[e * OUTD + o0];
            acc.x += c * w.x;
            acc.y += c * w.y;
            acc.z += c * w.z;
            acc.w += c * w.w;
        }
    }
    float mx = ok ? fmaxf(fmaxf(acc.x, acc.y), fmaxf(acc.z, acc.w)) : -INFINITY;
    red[tid] = mx;
    __syncthreads();
    for (int s = 128; s > 0; s >>= 1) {
        if (tid < s) red[tid] = fmaxf(red[tid], red[tid + s]);
        __syncthreads();
    }
    float M = red[0];
    __syncthreads();
    float4 p = {0.f, 0.f, 0.f, 0.f};
    float ls = 0.f;
    if (ok) {
        p.x = expf(acc.x - M);
        p.y = expf(acc.y - M);
        p.z = expf(acc.z - M);
        p.w = expf(acc.w - M);
        ls = p.x + p.y + p.z + p.w;
    }
    red[tid] = ls;
    __syncthreads();
    for (int s = 128; s > 0; s >>= 1) {
        if (tid < s) red[tid] += red[tid + s];
        __syncthreads();
    }
    float inv = 1.0f / red[0];
    if (ok) {
        p.x *= inv; p.y *= inv; p.z *= inv; p.w *= inv;
        *(float4*)&dout[b * OUTD + o0] = p;
    }
}

extern "C" void kernel_launch(void* const* d_in, const int* in_sizes, int n_in,
                              void* d_out, int out_size, void* d_ws, size_t ws_size,
                              hipStream_t stream) {
    const float* images  = (const float*)d_in[0];
    const float* W_map   = (const float*)d_in[1];
    const float* b_map   = (const float*)d_in[2];
    const float* cls_tok = (const float*)d_in[3];
    const float* ln1_g   = (const float*)d_in[4];
    const float* ln1_b   = (const float*)d_in[5];
    const float* Wq      = (const float*)d_in[6];
    const float* bq      = (const float*)d_in[7];
    const float* Wk      = (const float*)d_in[8];
    const float* bk      = (const float*)d_in[9];
    const float* Wv      = (const float*)d_in[10];
    const float* bv      = (const float*)d_in[11];
    const float* ln2_g   = (const float*)d_in[12];
    const float* ln2_b   = (const float*)d_in[13];
    const float* W_enc   = (const float*)d_in[14];
    const float* b_enc   = (const float*)d_in[15];
    const float* W_out   = (const float*)d_in[16];
    const float* b_out   = (const float*)d_in[17];

    float* ws = (float*)d_ws;
    const size_t BIG = (size_t)BATCH * SEQL * HD;     // 9,682,944
    const size_t QKB = (size_t)BATCH * 12 * 256 * 64; // 12,582,912 u16 per buffer

    float* pos   = ws;
    float* tok   = ws + 151552;
    float* outb  = tok + BIG;
    float* stats = outb + BIG;
    ushort_t* q16  = (ushort_t*)(stats + 256);
    ushort_t* k16  = q16 + QKB;
    ushort_t* vt16 = k16 + QKB;
    ushort_t* xb   = vt16 + QKB;                      // bf16 [12672][768] (pad rows unwritten)
    ushort_t* wtq  = xb + (size_t)12672 * 768;        // bf16 [3][12][64][64]

    // overlays (regions dead at time of use):
    ushort_t* Ae  = q16;                              // patches bf16 (dead before k_qkv_mfma)
    ushort_t* WmT = k16;                              // W_map^T bf16
    ushort_t* Ae2 = q16;                              // LN2-out bf16 (q16 dead after attn)
    ushort_t* WeT = k16;                              // W_enc^T bf16 (k16 dead after attn)

    k_pos<<<591, 256, 0, stream>>>(pos);
    k_cls<<<192, 256, 0, stream>>>(cls_tok, pos, tok);
    k_cvtW<<<576, 256, 0, stream>>>(W_map, WmT);
    k_prep_patches<<<9408, 256, 0, stream>>>(images, Ae);
    k_gemm_bf16<0><<<dim3(98, 6), 256, 0, stream>>>(Ae, WmT, b_map, pos, tok, 12544);
    k_lnstats<<<64, 256, 0, stream>>>(tok, stats, 0);
    k_ln1<<<9456, 256, 0, stream>>>(tok, stats, ln1_g, ln1_b, xb);
    k_cvtWqkv<<<144, 256, 0, stream>>>(Wq, Wk, Wv, wtq);
    k_qkv_mfma<<<dim3(2, 12, 64), 256, 0, stream>>>(xb, wtq, bq, bk, bv, q16, k16, vt16);
    k_attn_mfma<<<dim3(12, 64), 512, 0, stream>>>(q16, k16, vt16, tok, outb);
    k_cvtW<<<576, 256, 0, stream>>>(W_enc, WeT);
    k_lnstats<<<64, 256, 0, stream>>>(outb, stats, 1);
    k_ln2apply<<<9456, 256, 0, stream>>>(outb, stats, ln2_g, ln2_b, Ae2);
    k_gemm_bf16<1><<<dim3(99, 6), 256, 0, stream>>>(Ae2, WeT, b_enc, pos, outb, 12608);
    k_head<<<64, 256, 0, stream>>>(outb, W_out, b_out, (float*)d_out);
}

// Round 8
// 348.986 us; speedup vs baseline: 1.1582x; 1.1582x over previous
//
#include <hip/hip_runtime.h>
#include <math.h>

#define SEQL 197
#define HD 768
#define NH 12
#define DHD 64
#define BATCH 64
#define OUTD 1000

typedef unsigned short ushort_t;
typedef __attribute__((ext_vector_type(8))) short bf16x8;
typedef __attribute__((ext_vector_type(4))) float f32x4;

static __device__ __forceinline__ unsigned short f2bf(float f) {
    union { float f; unsigned u; } v; v.f = f;
    unsigned r = v.u + 0x7fff + ((v.u >> 16) & 1);
    return (unsigned short)(r >> 16);
}

static __device__ __forceinline__ void gload16(const ushort_t* g, ushort_t* l) {
    __builtin_amdgcn_global_load_lds(
        (const __attribute__((address_space(1))) unsigned int*)g,
        (__attribute__((address_space(3))) unsigned int*)l, 16, 0, 0);
}

// ---------------- positional embedding table ----------------
__global__ void k_pos(float* __restrict__ pos) {
    int i = blockIdx.x * 256 + threadIdx.x;
    if (i >= SEQL * HD) return;
    int s = i / HD, d = i % HD;
    float f = (float)(d & ~1);
    float r = powf(10000.0f, -f / (float)HD);
    float a = (float)s * r;
    pos[i] = (d & 1) ? cosf(a) : sinf(a);
}

// ---------------- cls row of tokens ----------------
__global__ void k_cls(const float* __restrict__ cls_tok, const float* __restrict__ pos,
                      float* __restrict__ tok) {
    int i = blockIdx.x * 256 + threadIdx.x;
    if (i >= BATCH * HD) return;
    int b = i / HD, e = i % HD;
    tok[(b * SEQL) * HD + e] = cls_tok[e] + pos[e];
}

// ---------------- W (f32 [K][N]) -> W^T bf16 [N][K], K=N=768 ----------------
__global__ void k_cvtW(const float* __restrict__ W, ushort_t* __restrict__ WT) {
    int idx = blockIdx.x * 256 + threadIdx.x;       // 0 .. 768*192
    if (idx >= 768 * 192) return;
    int k = idx / 192, nq = idx % 192;
    float4 w = *(const float4*)&W[k * 768 + nq * 4];
    WT[(nq * 4 + 0) * 768 + k] = f2bf(w.x);
    WT[(nq * 4 + 1) * 768 + k] = f2bf(w.y);
    WT[(nq * 4 + 2) * 768 + k] = f2bf(w.z);
    WT[(nq * 4 + 3) * 768 + k] = f2bf(w.w);
}

// ---------------- Wq/Wk/Wv [12][64 d][64 e] f32 -> wt bf16 [3][12][64 e][64 d] ----
__global__ void k_cvtWqkv(const float* __restrict__ Wq, const float* __restrict__ Wk,
                          const float* __restrict__ Wv, ushort_t* __restrict__ wt) {
    int idx = blockIdx.x * 256 + threadIdx.x;       // over 3*12*64*16 = 36864
    if (idx >= 36864) return;
    int dq = idx & 15;
    int e  = (idx >> 4) & 63;
    int h  = (idx >> 10) % 12;
    int pj = idx / 12288;
    const float* W = (pj == 0) ? Wq : (pj == 1) ? Wk : Wv;
    ushort4 o;
    o.x = f2bf(W[(h * 64 + dq * 4 + 0) * 64 + e]);
    o.y = f2bf(W[(h * 64 + dq * 4 + 1) * 64 + e]);
    o.z = f2bf(W[(h * 64 + dq * 4 + 2) * 64 + e]);
    o.w = f2bf(W[(h * 64 + dq * 4 + 3) * 64 + e]);
    *(ushort4*)&wt[(size_t)((pj * 12 + h) * 64 + e) * 64 + dq * 4] = o;
}

// ---------------- gather patches -> bf16 A [12544][768] ----------------
__global__ void k_prep_patches(const float* __restrict__ img, ushort_t* __restrict__ Ae) {
    int idx = blockIdx.x * 256 + threadIdx.x;       // 0 .. 12544*192
    int m = idx / 192, kq = idx % 192;
    int k0 = kq * 4;
    int c = k0 >> 8, rem = k0 & 255, ir = rem >> 4, jc = rem & 15;
    int b = m / 196, pi = m % 196;
    int pr = pi / 14, pc = pi % 14;
    float4 v = *(const float4*)&img[((b * 3 + c) * 224 + pr * 16 + ir) * 224 + pc * 16 + jc];
    ushort4 o;
    o.x = f2bf(v.x); o.y = f2bf(v.y); o.z = f2bf(v.z); o.w = f2bf(v.w);
    *(ushort4*)&Ae[m * 768 + k0] = o;
}

// ---------------- bf16 MFMA GEMM, 128x128 tile, BK=64, 4 waves ----------------
template <int MODE>
__launch_bounds__(256)
__global__ void k_gemm_bf16(const ushort_t* __restrict__ A, const ushort_t* __restrict__ Bt,
                            const float* __restrict__ bias, const float* __restrict__ pos,
                            float* __restrict__ out, int Mtot) {
    __shared__ ushort_t As[128 * 64];
    __shared__ ushort_t Bs[128 * 64];
    const int m0 = blockIdx.x * 128;
    const int n0 = blockIdx.y * 128;
    const int tid = threadIdx.x;
    const int lane = tid & 63, wave = tid >> 6;
    const int wm = wave >> 1, wn = wave & 1;

    f32x4 acc[4][4];
#pragma unroll
    for (int i = 0; i < 4; ++i)
#pragma unroll
        for (int j = 0; j < 4; ++j)
#pragma unroll
            for (int r = 0; r < 4; ++r) acc[i][j][r] = 0.f;

    for (int kt = 0; kt < 12; ++kt) {
        const int k0 = kt * 64;
#pragma unroll
        for (int t = 0; t < 4; ++t) {
            int c = (wave << 2) | t;
            int o = c * 1024 + lane * 16;
            int row = o >> 7;
            int inner = o & 127;
            int col = (inner ^ ((row & 7) << 4)) >> 1;
            gload16(&A[(size_t)(m0 + row) * 768 + k0 + col], &As[c * 512]);
            gload16(&Bt[(size_t)(n0 + row) * 768 + k0 + col], &Bs[c * 512]);
        }
        __syncthreads();
#pragma unroll
        for (int ks = 0; ks < 2; ++ks) {
            const int cbyte = ks * 64 + (lane >> 4) * 16;
            bf16x8 af[4], bf[4];
#pragma unroll
            for (int mi = 0; mi < 4; ++mi) {
                int row = wm * 64 + mi * 16 + (lane & 15);
                af[mi] = *(const bf16x8*)((const char*)As + row * 128 + (cbyte ^ ((row & 7) << 4)));
            }
#pragma unroll
            for (int ni = 0; ni < 4; ++ni) {
                int n = wn * 64 + ni * 16 + (lane & 15);
                bf[ni] = *(const bf16x8*)((const char*)Bs + n * 128 + (cbyte ^ ((n & 7) << 4)));
            }
#pragma unroll
            for (int mi = 0; mi < 4; ++mi)
#pragma unroll
                for (int ni = 0; ni < 4; ++ni)
                    acc[mi][ni] = __builtin_amdgcn_mfma_f32_16x16x32_bf16(af[mi], bf[ni], acc[mi][ni], 0, 0, 0);
        }
        __syncthreads();
    }

    const int colb = n0 + wn * 64 + (lane & 15);
    const int rowb = m0 + wm * 64 + (lane >> 4) * 4;
#pragma unroll
    for (int ni = 0; ni < 4; ++ni) {
        const int n = colb + ni * 16;
        const float bn = bias[n];
#pragma unroll
        for (int mi = 0; mi < 4; ++mi) {
#pragma unroll
            for (int r = 0; r < 4; ++r) {
                int m = rowb + mi * 16 + r;
                if (MODE == 0) {
                    int b = m / 196, s = 1 + m % 196;
                    out[((b * SEQL) + s) * HD + n] = acc[mi][ni][r] + bn + pos[s * HD + n];
                } else {
                    if (m < Mtot) {
                        float* p = &out[(size_t)m * HD + n];
                        *p = *p + fmaxf(acc[mi][ni][r] + bn, 0.f);
                    }
                }
            }
        }
    }
}

// ---------------- 2D LayerNorm stats (mean, rsigma) per image ----------------
__global__ void k_lnstats(const float* __restrict__ buf, float* __restrict__ stats, int which) {
    int b = blockIdx.x;
    const float* p = buf + (size_t)b * SEQL * HD;
    float s = 0.f, s2 = 0.f;
    const int NV = SEQL * HD / 4;
    for (int i = threadIdx.x; i < NV; i += 256) {
        float4 v = ((const float4*)p)[i];
        s += v.x + v.y + v.z + v.w;
        s2 += v.x * v.x + v.y * v.y + v.z * v.z + v.w * v.w;
    }
    __shared__ float rs[8], rs2[8];
#pragma unroll
    for (int off = 32; off > 0; off >>= 1) {
        s += __shfl_down(s, off);
        s2 += __shfl_down(s2, off);
    }
    int lane = threadIdx.x & 63, w = threadIdx.x >> 6;
    if (lane == 0) { rs[w] = s; rs2[w] = s2; }
    __syncthreads();
    if (threadIdx.x == 0) {
        float S = 0.f, S2 = 0.f;
        for (int i = 0; i < 4; ++i) { S += rs[i]; S2 += rs2[i]; }
        const float inv_n = 1.0f / (float)(SEQL * HD);
        float mu = S * inv_n;
        float var = S2 * inv_n - mu * mu;
        stats[which * 128 + b * 2] = mu;
        stats[which * 128 + b * 2 + 1] = rsqrtf(var + 1e-5f);
    }
}

// ---------------- FUSED: LN1 + QKV projections + flash attention + residual ----
// One block per (h, b), 8 waves. LDS (u16 units):
//   [0,16384):     Xs [256][64] XOR-swizzled; per-wave 2048-slice reused as Qtmp then P
//   [16384,34816): K  [256][72]
//   [34816,51712): V^T [64][264]
__launch_bounds__(512, 2)
__global__ void k_qkvattn(const float* __restrict__ tok, const float* __restrict__ stats,
                          const float* __restrict__ g1, const float* __restrict__ b1,
                          const ushort_t* __restrict__ wt,
                          const float* __restrict__ bq, const float* __restrict__ bk,
                          const float* __restrict__ bv, float* __restrict__ out) {
    const int h = blockIdx.x, b = blockIdx.y;
    __shared__ __attribute__((aligned(16))) ushort_t sm[51712];
    const int tid = threadIdx.x;
    const int wave = tid >> 6, lane = tid & 63;
    const int l16 = lane & 15, l4 = lane >> 4;
    const int r0 = wave * 32;
    const float mu = stats[b * 2], rsg = stats[b * 2 + 1];

    // ---- stage LN1(X) rows (each wave stages exactly its own 32 rows) ----
    {
        const int row = tid >> 1, hw = tid & 1;
        if (row < SEQL) {
            const float* tp = &tok[((size_t)b * SEQL + row) * HD + h * 64 + hw * 32];
            const float* gp = &g1[(size_t)row * HD + h * 64 + hw * 32];
            const float* bp = &b1[(size_t)row * HD + h * 64 + hw * 32];
#pragma unroll
            for (int g = 0; g < 4; ++g) {
                float4 t0 = *(const float4*)&tp[g * 8];
                float4 t1 = *(const float4*)&tp[g * 8 + 4];
                float4 ga = *(const float4*)&gp[g * 8];
                float4 gb = *(const float4*)&gp[g * 8 + 4];
                float4 ba = *(const float4*)&bp[g * 8];
                float4 bb = *(const float4*)&bp[g * 8 + 4];
                bf16x8 o;
                o[0] = (short)f2bf((t0.x - mu) * rsg * ga.x + ba.x);
                o[1] = (short)f2bf((t0.y - mu) * rsg * ga.y + ba.y);
                o[2] = (short)f2bf((t0.z - mu) * rsg * ga.z + ba.z);
                o[3] = (short)f2bf((t0.w - mu) * rsg * ga.w + ba.w);
                o[4] = (short)f2bf((t1.x - mu) * rsg * gb.x + bb.x);
                o[5] = (short)f2bf((t1.y - mu) * rsg * gb.y + bb.y);
                o[6] = (short)f2bf((t1.z - mu) * rsg * gb.z + bb.z);
                o[7] = (short)f2bf((t1.w - mu) * rsg * gb.w + bb.w);
                int pc = (hw * 32 + g * 8) ^ ((row & 7) << 3);
                *(bf16x8*)&sm[row * 64 + pc] = o;
            }
        } else {
            bf16x8 z;
#pragma unroll
            for (int j = 0; j < 8; ++j) z[j] = 0;
#pragma unroll
            for (int g = 0; g < 4; ++g) {
                int pc = (hw * 32 + g * 8) ^ ((row & 7) << 3);
                *(bf16x8*)&sm[row * 64 + pc] = z;
            }
        }
    }

    // A fragments from own rows (wave-private slice; no barrier needed)
    bf16x8 af[2][2];
#pragma unroll
    for (int mi = 0; mi < 2; ++mi)
#pragma unroll
        for (int kk = 0; kk < 2; ++kk) {
            int row = r0 + mi * 16 + l16;
            af[mi][kk] = *(const bf16x8*)&sm[row * 64 + ((kk * 32 + l4 * 8) ^ ((row & 7) << 3))];
        }

    ushort_t* myS = &sm[wave * 2048];   // wave-private 32x64 slice (Qtmp, then P)

#define PROJ_ACC(PJ, ACC)                                                                      \
    {                                                                                          \
        _Pragma("unroll") for (int ni = 0; ni < 4; ++ni) {                                     \
            const ushort_t* wr = &wt[(size_t)(((PJ) * 12 + h) * 64 + ni * 16 + l16) * 64];     \
            bf16x8 w0 = *(const bf16x8*)&wr[l4 * 8];                                           \
            bf16x8 w1 = *(const bf16x8*)&wr[32 + l4 * 8];                                      \
            _Pragma("unroll") for (int mi = 0; mi < 2; ++mi) {                                 \
                ACC[mi][ni] = __builtin_amdgcn_mfma_f32_16x16x32_bf16(af[mi][0], w0, ACC[mi][ni], 0, 0, 0); \
                ACC[mi][ni] = __builtin_amdgcn_mfma_f32_16x16x32_bf16(af[mi][1], w1, ACC[mi][ni], 0, 0, 0); \
            }                                                                                  \
        }                                                                                      \
    }

    f32x4 acc[2][4];
#define ZERO_ACC                                                                               \
    _Pragma("unroll") for (int mi = 0; mi < 2; ++mi)                                           \
        _Pragma("unroll") for (int ni = 0; ni < 4; ++ni) {                                     \
            acc[mi][ni][0] = 0.f; acc[mi][ni][1] = 0.f; acc[mi][ni][2] = 0.f; acc[mi][ni][3] = 0.f; }

    // ---- Q ----
    ZERO_ACC;
    PROJ_ACC(0, acc);
#pragma unroll
    for (int ni = 0; ni < 4; ++ni) {
        float bn = bq[h * 64 + ni * 16 + l16];
#pragma unroll
        for (int mi = 0; mi < 2; ++mi)
#pragma unroll
            for (int r = 0; r < 4; ++r) {
                int rl = mi * 16 + l4 * 4 + r;
                myS[rl * 64 + ((ni * 16 + l16) ^ ((rl & 7) << 3))] = f2bf(acc[mi][ni][r] + bn);
            }
    }
    bf16x8 qa[2][2];
#pragma unroll
    for (int mi = 0; mi < 2; ++mi)
#pragma unroll
        for (int kk = 0; kk < 2; ++kk) {
            int rl = mi * 16 + l16;
            qa[mi][kk] = *(const bf16x8*)&myS[rl * 64 + ((kk * 32 + l4 * 8) ^ ((rl & 7) << 3))];
        }

    // ---- K ----
    ZERO_ACC;
    PROJ_ACC(1, acc);
#pragma unroll
    for (int ni = 0; ni < 4; ++ni) {
        float bn = bk[h * 64 + ni * 16 + l16];
#pragma unroll
        for (int mi = 0; mi < 2; ++mi)
#pragma unroll
            for (int r = 0; r < 4; ++r) {
                int t = r0 + mi * 16 + l4 * 4 + r;
                sm[16384 + t * 72 + ni * 16 + l16] = f2bf(acc[mi][ni][r] + bn);
            }
    }

    // ---- V (transposed store) ----
    ZERO_ACC;
    PROJ_ACC(2, acc);
#pragma unroll
    for (int ni = 0; ni < 4; ++ni) {
        float bn = bv[h * 64 + ni * 16 + l16];
#pragma unroll
        for (int mi = 0; mi < 2; ++mi)
#pragma unroll
            for (int r = 0; r < 4; ++r) {
                int t = r0 + mi * 16 + l4 * 4 + r;
                sm[34816 + (ni * 16 + l16) * 264 + t] = f2bf(acc[mi][ni][r] + bn);
            }
    }

    __syncthreads();   // K and V^T now visible to all waves

    // ---- QK^T over all 256 t ----
    f32x4 sa[2][16];
#pragma unroll
    for (int ni = 0; ni < 16; ++ni) {
        int t = ni * 16 + l16;
        bf16x8 k0 = *(const bf16x8*)&sm[16384 + t * 72 + l4 * 8];
        bf16x8 k1 = *(const bf16x8*)&sm[16384 + t * 72 + 32 + l4 * 8];
#pragma unroll
        for (int mi = 0; mi < 2; ++mi) {
            f32x4 z;
            z[0] = 0.f; z[1] = 0.f; z[2] = 0.f; z[3] = 0.f;
            z = __builtin_amdgcn_mfma_f32_16x16x32_bf16(qa[mi][0], k0, z, 0, 0, 0);
            sa[mi][ni] = __builtin_amdgcn_mfma_f32_16x16x32_bf16(qa[mi][1], k1, z, 0, 0, 0);
        }
    }

    // ---- full softmax per q-row ----
    float l_s[2][4];
#pragma unroll
    for (int mi = 0; mi < 2; ++mi)
#pragma unroll
        for (int r = 0; r < 4; ++r) {
            float mt = -INFINITY;
#pragma unroll
            for (int ni = 0; ni < 16; ++ni) {
                float s = sa[mi][ni][r] * 0.125f;
                if (ni * 16 + l16 >= SEQL) s = -1e30f;
                sa[mi][ni][r] = s;
                mt = fmaxf(mt, s);
            }
            mt = fmaxf(mt, __shfl_xor(mt, 1));
            mt = fmaxf(mt, __shfl_xor(mt, 2));
            mt = fmaxf(mt, __shfl_xor(mt, 4));
            mt = fmaxf(mt, __shfl_xor(mt, 8));
            float rsum = 0.f;
#pragma unroll
            for (int ni = 0; ni < 16; ++ni) {
                float p = __expf(sa[mi][ni][r] - mt);
                sa[mi][ni][r] = p;
                rsum += p;
            }
            rsum += __shfl_xor(rsum, 1);
            rsum += __shfl_xor(rsum, 2);
            rsum += __shfl_xor(rsum, 4);
            rsum += __shfl_xor(rsum, 8);
            l_s[mi][r] = rsum;
        }

    // ---- PV in 4 chunks of 64 t (P bounced through wave-private slice) ----
    f32x4 oacc[2][4];
#pragma unroll
    for (int mi = 0; mi < 2; ++mi)
#pragma unroll
        for (int ne = 0; ne < 4; ++ne) {
            oacc[mi][ne][0] = 0.f; oacc[mi][ne][1] = 0.f;
            oacc[mi][ne][2] = 0.f; oacc[mi][ne][3] = 0.f;
        }

    for (int c = 0; c < 4; ++c) {
#pragma unroll
        for (int j = 0; j < 4; ++j)
#pragma unroll
            for (int mi = 0; mi < 2; ++mi)
#pragma unroll
                for (int r = 0; r < 4; ++r) {
                    int rl = mi * 16 + l4 * 4 + r;
                    myS[rl * 64 + ((j * 16 + l16) ^ ((rl & 7) << 3))] = f2bf(sa[mi][c * 4 + j][r]);
                }
        bf16x8 pa[2][2];
#pragma unroll
        for (int mi = 0; mi < 2; ++mi)
#pragma unroll
            for (int kk = 0; kk < 2; ++kk) {
                int rl = mi * 16 + l16;
                pa[mi][kk] = *(const bf16x8*)&myS[rl * 64 + ((kk * 32 + l4 * 8) ^ ((rl & 7) << 3))];
            }
#pragma unroll
        for (int ne = 0; ne < 4; ++ne) {
            int e = ne * 16 + l16;
            bf16x8 v0 = *(const bf16x8*)&sm[34816 + e * 264 + c * 64 + l4 * 8];
            bf16x8 v1 = *(const bf16x8*)&sm[34816 + e * 264 + c * 64 + 32 + l4 * 8];
#pragma unroll
            for (int mi = 0; mi < 2; ++mi) {
                oacc[mi][ne] = __builtin_amdgcn_mfma_f32_16x16x32_bf16(pa[mi][0], v0, oacc[mi][ne], 0, 0, 0);
                oacc[mi][ne] = __builtin_amdgcn_mfma_f32_16x16x32_bf16(pa[mi][1], v1, oacc[mi][ne], 0, 0, 0);
            }
        }
    }

    // ---- epilogue: O/l + residual ----
#pragma unroll
    for (int mi = 0; mi < 2; ++mi)
#pragma unroll
        for (int r = 0; r < 4; ++r) {
            int row = r0 + mi * 16 + l4 * 4 + r;
            if (row < SEQL) {
                float inv = 1.0f / l_s[mi][r];
                size_t off = ((size_t)b * SEQL + row) * HD + h * 64;
#pragma unroll
                for (int ne = 0; ne < 4; ++ne) {
                    int e = ne * 16 + l16;
                    out[off + e] = oacc[mi][ne][r] * inv + tok[off + e];
                }
            }
        }
#undef PROJ_ACC
#undef ZERO_ACC
}

// ---------------- LN2 apply -> bf16 A for encoder GEMM ----------------
__global__ void k_ln2apply(const float* __restrict__ outb, const float* __restrict__ stats,
                           const float* __restrict__ g2, const float* __restrict__ b2,
                           ushort_t* __restrict__ x) {
    int i = blockIdx.x * 256 + threadIdx.x;
    if (i >= BATCH * SEQL * HD / 4) return;
    int e4 = i * 4;
    int m = e4 / HD, kk = e4 % HD;
    int b = m / SEQL, s = m % SEQL;
    float mu = stats[128 + b * 2], rsg = stats[128 + b * 2 + 1];
    float4 t = *(const float4*)&outb[e4];
    float4 g = *(const float4*)&g2[s * HD + kk];
    float4 bb = *(const float4*)&b2[s * HD + kk];
    ushort4 o;
    o.x = f2bf((t.x - mu) * rsg * g.x + bb.x);
    o.y = f2bf((t.y - mu) * rsg * g.y + bb.y);
    o.z = f2bf((t.z - mu) * rsg * g.z + bb.z);
    o.w = f2bf((t.w - mu) * rsg * g.w + bb.w);
    *(ushort4*)&x[e4] = o;
}

// ---------------- classifier head + softmax ----------------
__launch_bounds__(256)
__global__ void k_head(const float* __restrict__ out, const float* __restrict__ Wo,
                       const float* __restrict__ bo, float* __restrict__ dout) {
    const int b = blockIdx.x, tid = threadIdx.x;
    __shared__ float cls[768];
    __shared__ float red[256];
    for (int i = tid; i < 192; i += 256)
        *(float4*)&cls[i * 4] = *(const float4*)&out[(b * SEQL) * HD + i * 4];
    __syncthreads();

    const int o0 = tid * 4;
    const bool ok = (o0 < OUTD);
    float4 acc = {0.f, 0.f, 0.f, 0.f};
    if (ok) {
        acc = *(const float4*)&bo[o0];
        for (int e = 0; e < 768; ++e) {
            float c = cls[e];
            float4 w = *(const float4*)&Wo[e * OUTD + o0];
            acc.x += c * w.x;
            acc.y += c * w.y;
            acc.z += c * w.z;
            acc.w += c * w.w;
        }
    }
    float mx = ok ? fmaxf(fmaxf(acc.x, acc.y), fmaxf(acc.z, acc.w)) : -INFINITY;
    red[tid] = mx;
    __syncthreads();
    for (int s = 128; s > 0; s >>= 1) {
        if (tid < s) red[tid] = fmaxf(red[tid], red[tid + s]);
        __syncthreads();
    }
    float M = red[0];
    __syncthreads();
    float4 p = {0.f, 0.f, 0.f, 0.f};
    float ls = 0.f;
    if (ok) {
        p.x = expf(acc.x - M);
        p.y = expf(acc.y - M);
        p.z = expf(acc.z - M);
        p.w = expf(acc.w - M);
        ls = p.x + p.y + p.z + p.w;
    }
    red[tid] = ls;
    __syncthreads();
    for (int s = 128; s > 0; s >>= 1) {
        if (tid < s) red[tid] += red[tid + s];
        __syncthreads();
    }
    float inv = 1.0f / red[0];
    if (ok) {
        p.x *= inv; p.y *= inv; p.z *= inv; p.w *= inv;
        *(float4*)&dout[b * OUTD + o0] = p;
    }
}

extern "C" void kernel_launch(void* const* d_in, const int* in_sizes, int n_in,
                              void* d_out, int out_size, void* d_ws, size_t ws_size,
                              hipStream_t stream) {
    const float* images  = (const float*)d_in[0];
    const float* W_map   = (const float*)d_in[1];
    const float* b_map   = (const float*)d_in[2];
    const float* cls_tok = (const float*)d_in[3];
    const float* ln1_g   = (const float*)d_in[4];
    const float* ln1_b   = (const float*)d_in[5];
    const float* Wq      = (const float*)d_in[6];
    const float* bq      = (const float*)d_in[7];
    const float* Wk      = (const float*)d_in[8];
    const float* bk      = (const float*)d_in[9];
    const float* Wv      = (const float*)d_in[10];
    const float* bv      = (const float*)d_in[11];
    const float* ln2_g   = (const float*)d_in[12];
    const float* ln2_b   = (const float*)d_in[13];
    const float* W_enc   = (const float*)d_in[14];
    const float* b_enc   = (const float*)d_in[15];
    const float* W_out   = (const float*)d_in[16];
    const float* b_out   = (const float*)d_in[17];

    float* ws = (float*)d_ws;
    const size_t BIG = (size_t)BATCH * SEQL * HD;     // 9,682,944

    float* pos   = ws;
    float* tok   = ws + 151552;
    float* outb  = tok + BIG;
    float* stats = outb + BIG;                        // 256 f32
    ushort_t* wtq = (ushort_t*)(stats + 256);         // bf16 [3][12][64][64] = 36864
    // Ae sized 12672 rows: holds 12544-row patch matrix AND the 12608-row LN2
    // output (the round-6 bug: 12544 rows overflowed into WmT/WeT), plus the
    // enc GEMM's 12672-row tail-tile reads stay in-bounds (masked, finite).
    ushort_t* Ae  = wtq + 36864;                      // bf16 [12672][768]
    ushort_t* WmT = Ae + (size_t)12672 * 768;         // bf16 [768][768]
    // overlays (dead regions reused):
    ushort_t* Ae2 = Ae;                               // LN2-out bf16 (Ae dead after embed GEMM)
    ushort_t* WeT = WmT;                              // W_enc^T bf16 (WmT dead after embed GEMM)

    k_pos<<<591, 256, 0, stream>>>(pos);
    k_cls<<<192, 256, 0, stream>>>(cls_tok, pos, tok);
    k_cvtW<<<576, 256, 0, stream>>>(W_map, WmT);
    k_prep_patches<<<9408, 256, 0, stream>>>(images, Ae);
    k_gemm_bf16<0><<<dim3(98, 6), 256, 0, stream>>>(Ae, WmT, b_map, pos, tok, 12544);
    k_lnstats<<<64, 256, 0, stream>>>(tok, stats, 0);
    k_cvtWqkv<<<144, 256, 0, stream>>>(Wq, Wk, Wv, wtq);
    k_qkvattn<<<dim3(12, 64), 512, 0, stream>>>(tok, stats, ln1_g, ln1_b, wtq, bq, bk, bv, outb);
    k_cvtW<<<576, 256, 0, stream>>>(W_enc, WeT);
    k_lnstats<<<64, 256, 0, stream>>>(outb, stats, 1);
    k_ln2apply<<<9456, 256, 0, stream>>>(outb, stats, ln2_g, ln2_b, Ae2);
    k_gemm_bf16<1><<<dim3(99, 6), 256, 0, stream>>>(Ae2, WeT, b_enc, pos, outb, 12608);
    k_head<<<64, 256, 0, stream>>>(outb, W_out, b_out, (float*)d_out);
}